// Round 1
// baseline (209.539 us; speedup 1.0000x reference)
//
#include <hip/hip_runtime.h>
#include <hip/hip_bf16.h>

#define MARGIN 0.0625f

// Problem sizes (fixed by the reference)
#define B 64
#define N 64
#define P 4096        // B*N query points
#define M 100000      // means
#define G 512         // mean-chunks (blocks in main kernel)
#define CHUNK 196     // ceil(100000/512) -> 512*196 = 100352 (padded)
#define MPAD 100352
#define R 16          // queries per thread in main kernel (256*16 = 4096)

// ws layout (bytes):
//   mpack  : [0, 100352*16)                  = 1,605,632
//   qbuf   : [1605632, +4096*16)             = 65,536
//   partial: [1671168, +512*4096*4)          = 8,388,608
//   sums   : [10059776, +16*4)
// total ~10.06 MB
#define WS_MPACK_OFF   0
#define WS_QBUF_OFF    1605632
#define WS_PARTIAL_OFF 1671168
#define WS_SUMS_OFF    10059776

// ---------------------------------------------------------------------------
// Kernel 1: pack means (-2x,-2y,-2z,|m|^2) with sentinel padding, and compute
// query points qbuf[p] = (qx,qy,qz,|q|^2).
// q_i = s_b * sum_j c2w[b][i][j]*out[b][n][j] + c2w[b][i][3]
// ---------------------------------------------------------------------------
__global__ __launch_bounds__(256) void prep_kernel(
    const float* __restrict__ outputs,   // [B*N*3]
    const float* __restrict__ c2ws,      // [B*16]
    const float* __restrict__ scales,    // [B]
    const float* __restrict__ means,     // [M*3]
    float4* __restrict__ mpack,          // [MPAD]
    float4* __restrict__ qbuf)           // [P]
{
    int idx = blockIdx.x * 256 + threadIdx.x;
    if (idx < MPAD) {
        if (idx < M) {
            float x = means[3 * idx + 0];
            float y = means[3 * idx + 1];
            float z = means[3 * idx + 2];
            float mm = fmaf(x, x, fmaf(y, y, z * z));
            mpack[idx] = make_float4(-2.0f * x, -2.0f * y, -2.0f * z, mm);
        } else {
            mpack[idx] = make_float4(0.0f, 0.0f, 0.0f, 1e30f);  // never wins the min
        }
    }
    if (idx < P) {
        int b = idx >> 6;
        float s  = scales[b];
        float o0 = outputs[3 * idx + 0];
        float o1 = outputs[3 * idx + 1];
        float o2 = outputs[3 * idx + 2];
        const float* cw = c2ws + b * 16;
        float q0 = fmaf(s, fmaf(cw[0],  o0, fmaf(cw[1],  o1, cw[2]  * o2)), cw[3]);
        float q1 = fmaf(s, fmaf(cw[4],  o0, fmaf(cw[5],  o1, cw[6]  * o2)), cw[7]);
        float q2 = fmaf(s, fmaf(cw[8],  o0, fmaf(cw[9],  o1, cw[10] * o2)), cw[11]);
        float qq = fmaf(q0, q0, fmaf(q1, q1, q2 * q2));
        qbuf[idx] = make_float4(q0, q1, q2, qq);
    }
}

// ---------------------------------------------------------------------------
// Kernel 2: main NN scan. Block g scans means [g*CHUNK, (g+1)*CHUNK).
// Thread t holds R=16 queries (p = i*256 + t) in registers.
// Per mean (wave-uniform load -> SGPRs): d = fma(qx,m2x, fma(qy,m2y,
// fma(qz,m2z, mm))), min-accumulate. Epilogue: partial[g*P+p] =
// max(qq + min, 0)  (clamp commutes with min; keeps values >= 0).
// ---------------------------------------------------------------------------
__global__ __launch_bounds__(256) void nn_kernel(
    const float4* __restrict__ mpack,
    const float4* __restrict__ qbuf,
    float* __restrict__ partial)
{
    const int t = threadIdx.x;
    const int g = blockIdx.x;
    const int base = g * CHUNK;

    float qx[R], qy[R], qz[R], mn[R];
#pragma unroll
    for (int i = 0; i < R; ++i) {
        float4 q = qbuf[i * 256 + t];
        qx[i] = q.x; qy[i] = q.y; qz[i] = q.z;
        mn[i] = 1e30f;
    }

    for (int k = 0; k < CHUNK; ++k) {
        float4 m = mpack[base + k];   // wave-uniform -> scalar load + broadcast
#pragma unroll
        for (int i = 0; i < R; ++i) {
            float d = fmaf(qx[i], m.x, fmaf(qy[i], m.y, fmaf(qz[i], m.z, m.w)));
            mn[i] = fminf(mn[i], d);
        }
    }

#pragma unroll
    for (int i = 0; i < R; ++i) {
        int p = i * 256 + t;
        float qq = qbuf[p].w;
        partial[g * P + p] = fmaxf(qq + mn[i], 0.0f);   // clamped d2, >= 0
    }
}

// ---------------------------------------------------------------------------
// Kernel 3: per-query min over the G chunks, relu(MARGIN - d), block-sum.
// 16 blocks x 256 threads; block bid handles queries [bid*256, bid*256+256).
// ---------------------------------------------------------------------------
__global__ __launch_bounds__(256) void reduce_kernel(
    const float* __restrict__ partial,
    float* __restrict__ sums)
{
    const int t = threadIdx.x;
    const int p = blockIdx.x * 256 + t;

    float m = 1e30f;
    for (int g = 0; g < G; ++g)
        m = fminf(m, partial[g * P + p]);

    float v = fmaxf(MARGIN - m, 0.0f);

    // wave reduce (64 lanes)
#pragma unroll
    for (int off = 32; off > 0; off >>= 1)
        v += __shfl_down(v, off, 64);

    __shared__ float lds[4];
    int wid = t >> 6;
    if ((t & 63) == 0) lds[wid] = v;
    __syncthreads();
    if (t == 0)
        sums[blockIdx.x] = lds[0] + lds[1] + lds[2] + lds[3];
}

// ---------------------------------------------------------------------------
// Kernel 4: final scalar: mean over P of the 16 block sums.
// ---------------------------------------------------------------------------
__global__ __launch_bounds__(64) void final_kernel(
    const float* __restrict__ sums,
    float* __restrict__ out)
{
    int t = threadIdx.x;
    float v = (t < 16) ? sums[t] : 0.0f;
#pragma unroll
    for (int off = 8; off > 0; off >>= 1)
        v += __shfl_down(v, off, 64);
    if (t == 0)
        out[0] = v * (1.0f / (float)P);
}

extern "C" void kernel_launch(void* const* d_in, const int* in_sizes, int n_in,
                              void* d_out, int out_size, void* d_ws, size_t ws_size,
                              hipStream_t stream) {
    const float* outputs = (const float*)d_in[0];  // (64,64,3)
    const float* c2ws    = (const float*)d_in[1];  // (64,4,4)
    const float* scales  = (const float*)d_in[2];  // (64,)
    const float* means   = (const float*)d_in[3];  // (100000,3)

    char* ws = (char*)d_ws;
    float4* mpack  = (float4*)(ws + WS_MPACK_OFF);
    float4* qbuf   = (float4*)(ws + WS_QBUF_OFF);
    float* partial = (float*)(ws + WS_PARTIAL_OFF);
    float* sums    = (float*)(ws + WS_SUMS_OFF);
    float* out     = (float*)d_out;

    prep_kernel<<<(MPAD + 255) / 256, 256, 0, stream>>>(outputs, c2ws, scales,
                                                        means, mpack, qbuf);
    nn_kernel<<<G, 256, 0, stream>>>(mpack, qbuf, partial);
    reduce_kernel<<<16, 256, 0, stream>>>(partial, sums);
    final_kernel<<<1, 64, 0, stream>>>(sums, out);
}

// Round 2
// 110.778 us; speedup vs baseline: 1.8915x; 1.8915x over previous
//
#include <hip/hip_runtime.h>
#include <hip/hip_bf16.h>

#define MARGIN 0.0625f

// Problem sizes (fixed by the reference)
#define B 64
#define N 64
#define P 4096        // B*N query points
#define M 100000      // means
#define G 512         // mean-chunks along g
#define QS 2          // query slabs in nn grid
#define CHUNK 196     // 512*196 = 100352 (padded)
#define MPAD 100352
#define R 8           // queries per thread in nn kernel (256*8*QS = 4096)
#define H 16          // g-groups in reduce1
#define GPERH 32      // 512/16

// ws layout (bytes):
//   mpack   : [0, 100352*16)                  = 1,605,632
//   qbuf    : [1605632, +4096*16)             = 65,536
//   partial : [1671168, +512*4096*4)          = 8,388,608   total 10,059,776
//   partial2: aliases mpack[0..256KB) -- only live after nn_kernel is done
#define WS_MPACK_OFF   0
#define WS_QBUF_OFF    1605632
#define WS_PARTIAL_OFF 1671168
#define WS_PART2_OFF   0

// ---------------------------------------------------------------------------
// Kernel 1: pack means (-2x,-2y,-2z,|m|^2) with sentinel padding, compute
// query points qbuf[p] = (qx,qy,qz,|q|^2), and zero the output scalar.
// ---------------------------------------------------------------------------
__global__ __launch_bounds__(256) void prep_kernel(
    const float* __restrict__ outputs,   // [B*N*3]
    const float* __restrict__ c2ws,      // [B*16]
    const float* __restrict__ scales,    // [B]
    const float* __restrict__ means,     // [M*3]
    float4* __restrict__ mpack,          // [MPAD]
    float4* __restrict__ qbuf,           // [P]
    float* __restrict__ out)
{
    int idx = blockIdx.x * 256 + threadIdx.x;
    if (idx == 0) out[0] = 0.0f;          // accumulated later via atomicAdd
    if (idx < MPAD) {
        if (idx < M) {
            float x = means[3 * idx + 0];
            float y = means[3 * idx + 1];
            float z = means[3 * idx + 2];
            float mm = fmaf(x, x, fmaf(y, y, z * z));
            mpack[idx] = make_float4(-2.0f * x, -2.0f * y, -2.0f * z, mm);
        } else {
            mpack[idx] = make_float4(0.0f, 0.0f, 0.0f, 1e30f);  // never wins the min
        }
    }
    if (idx < P) {
        int b = idx >> 6;
        float s  = scales[b];
        float o0 = outputs[3 * idx + 0];
        float o1 = outputs[3 * idx + 1];
        float o2 = outputs[3 * idx + 2];
        const float* cw = c2ws + b * 16;
        float q0 = fmaf(s, fmaf(cw[0],  o0, fmaf(cw[1],  o1, cw[2]  * o2)), cw[3]);
        float q1 = fmaf(s, fmaf(cw[4],  o0, fmaf(cw[5],  o1, cw[6]  * o2)), cw[7]);
        float q2 = fmaf(s, fmaf(cw[8],  o0, fmaf(cw[9],  o1, cw[10] * o2)), cw[11]);
        float qq = fmaf(q0, q0, fmaf(q1, q1, q2 * q2));
        qbuf[idx] = make_float4(q0, q1, q2, qq);
    }
}

// ---------------------------------------------------------------------------
// Kernel 2: main NN scan. Grid (G, QS). Block (g, qs) scans means
// [g*CHUNK, (g+1)*CHUNK) against 2048 queries of slab qs; thread t holds
// R=8 queries in registers. Means processed in pairs -> v_min3_f32 fold.
// Epilogue: partial[g*P+p] = max(qq + min, 0).
// ---------------------------------------------------------------------------
__global__ __launch_bounds__(256) void nn_kernel(
    const float4* __restrict__ mpack,
    const float4* __restrict__ qbuf,
    float* __restrict__ partial)
{
    const int t  = threadIdx.x;
    const int g  = blockIdx.x;
    const int qs = blockIdx.y;
    const int base  = g * CHUNK;
    const int pbase = qs * (P / QS);

    float qx[R], qy[R], qz[R], mn[R];
#pragma unroll
    for (int i = 0; i < R; ++i) {
        float4 q = qbuf[pbase + i * 256 + t];
        qx[i] = q.x; qy[i] = q.y; qz[i] = q.z;
        mn[i] = 1e30f;
    }

#pragma unroll 2
    for (int k = 0; k < CHUNK; k += 2) {
        float4 m0 = mpack[base + k];       // wave-uniform -> scalar loads
        float4 m1 = mpack[base + k + 1];
#pragma unroll
        for (int i = 0; i < R; ++i) {
            float d0 = fmaf(qx[i], m0.x, fmaf(qy[i], m0.y, fmaf(qz[i], m0.z, m0.w)));
            float d1 = fmaf(qx[i], m1.x, fmaf(qy[i], m1.y, fmaf(qz[i], m1.z, m1.w)));
            mn[i] = fminf(fminf(d0, d1), mn[i]);   // v_min3_f32
        }
    }

#pragma unroll
    for (int i = 0; i < R; ++i) {
        int p = pbase + i * 256 + t;
        float qq = qbuf[p].w;
        partial[g * P + p] = fmaxf(qq + mn[i], 0.0f);   // clamped d2, >= 0
    }
}

// ---------------------------------------------------------------------------
// Kernel 3: stage-1 min. Grid (16 slabs, 16 g-groups). Block (s,h): for the
// 256 queries of slab s, min over g in [h*32,(h+1)*32); coalesced reads.
// ---------------------------------------------------------------------------
__global__ __launch_bounds__(256) void reduce1_kernel(
    const float* __restrict__ partial,
    float* __restrict__ partial2)        // [H*P]
{
    const int t = threadIdx.x;
    const int s = blockIdx.x;
    const int h = blockIdx.y;
    const int p = s * 256 + t;

    float m = 1e30f;
#pragma unroll
    for (int j = 0; j < GPERH; ++j)
        m = fminf(m, partial[(h * GPERH + j) * P + p]);

    partial2[h * P + p] = m;
}

// ---------------------------------------------------------------------------
// Kernel 4: stage-2 min over H=16 groups, relu(MARGIN-d)/P, block-sum,
// atomicAdd into out (zeroed by prep; same-stream kernels are ordered).
// ---------------------------------------------------------------------------
__global__ __launch_bounds__(256) void reduce2_kernel(
    const float* __restrict__ partial2,
    float* __restrict__ out)
{
    const int t = threadIdx.x;
    const int p = blockIdx.x * 256 + t;

    float m = 1e30f;
#pragma unroll
    for (int h = 0; h < H; ++h)
        m = fminf(m, partial2[h * P + p]);

    float v = fmaxf(MARGIN - m, 0.0f) * (1.0f / (float)P);

#pragma unroll
    for (int off = 32; off > 0; off >>= 1)
        v += __shfl_down(v, off, 64);

    __shared__ float lds[4];
    int wid = t >> 6;
    if ((t & 63) == 0) lds[wid] = v;
    __syncthreads();
    if (t == 0)
        atomicAdd(out, lds[0] + lds[1] + lds[2] + lds[3]);
}

extern "C" void kernel_launch(void* const* d_in, const int* in_sizes, int n_in,
                              void* d_out, int out_size, void* d_ws, size_t ws_size,
                              hipStream_t stream) {
    const float* outputs = (const float*)d_in[0];  // (64,64,3)
    const float* c2ws    = (const float*)d_in[1];  // (64,4,4)
    const float* scales  = (const float*)d_in[2];  // (64,)
    const float* means   = (const float*)d_in[3];  // (100000,3)

    char* ws = (char*)d_ws;
    float4* mpack   = (float4*)(ws + WS_MPACK_OFF);
    float4* qbuf    = (float4*)(ws + WS_QBUF_OFF);
    float* partial  = (float*)(ws + WS_PARTIAL_OFF);
    float* partial2 = (float*)(ws + WS_PART2_OFF);   // aliases mpack (dead by then)
    float* out      = (float*)d_out;

    prep_kernel<<<(MPAD + 255) / 256, 256, 0, stream>>>(outputs, c2ws, scales,
                                                        means, mpack, qbuf, out);
    nn_kernel<<<dim3(G, QS), 256, 0, stream>>>(mpack, qbuf, partial);
    reduce1_kernel<<<dim3(16, H), 256, 0, stream>>>(partial, partial2);
    reduce2_kernel<<<16, 256, 0, stream>>>(partial2, out);
}